// Round 7
// baseline (119.505 us; speedup 1.0000x reference)
//
#include <hip/hip_runtime.h>
#include <hip/hip_bf16.h>

#define B_ 4
#define C_ 64
#define N_ 4096
#define EPS_ 1e-5f
// p = exp(s*0.125) = exp2(s * 0.125*log2e); folded into stored q
#define C2_ 0.18033688011112042f

typedef __hip_bfloat16 bf16;
typedef __attribute__((ext_vector_type(8))) short short8;
typedef __attribute__((ext_vector_type(4))) short short4v;
typedef __attribute__((ext_vector_type(4))) float f32x4;

__device__ __forceinline__ float b2f(bf16 v) { return __bfloat162float(v); }

__device__ __forceinline__ short f2bs(float f) {
  union { bf16 h; short s; } u;
  u.h = __float2bfloat16(f);
  return u.s;
}

__device__ __forceinline__ short8 pk8(const float* f) {
  union { short8 v; short s[8]; } u;
#pragma unroll
  for (int i = 0; i < 8; ++i) u.s[i] = f2bs(f[i]);
  return u.v;
}

__device__ __forceinline__ void up8(short8 v, float* d) {
  union { short8 v; unsigned u[4]; } x;
  x.v = v;
  d[0] = __uint_as_float(x.u[0] << 16);
  d[1] = __uint_as_float(x.u[0] & 0xffff0000u);
  d[2] = __uint_as_float(x.u[1] << 16);
  d[3] = __uint_as_float(x.u[1] & 0xffff0000u);
  d[4] = __uint_as_float(x.u[2] << 16);
  d[5] = __uint_as_float(x.u[2] & 0xffff0000u);
  d[6] = __uint_as_float(x.u[3] << 16);
  d[7] = __uint_as_float(x.u[3] & 0xffff0000u);
}

__device__ __forceinline__ void up4(ushort4 u, float* d) {
  d[0] = __uint_as_float(((unsigned)u.x) << 16);
  d[1] = __uint_as_float(((unsigned)u.y) << 16);
  d[2] = __uint_as_float(((unsigned)u.z) << 16);
  d[3] = __uint_as_float(((unsigned)u.w) << 16);
}

template <bool F32>
__device__ __forceinline__ float ldx(const void* p, size_t idx) {
  if (F32) return ((const float*)p)[idx];
  return b2f(((const bf16*)p)[idx]);
}

template <bool F32>
__device__ __forceinline__ short8 ld8(const void* p, int idx) {
  if (F32) {
    const float* fp = (const float*)p + idx;
    float tmp[8];
    *(float4*)&tmp[0] = *(const float4*)fp;
    *(float4*)&tmp[4] = *(const float4*)(fp + 4);
    return pk8(tmp);
  }
  return *(const short8*)((const bf16*)p + idx);
}

__device__ __forceinline__ f32x4 mfma32(short8 a, short8 b, f32x4 c) {
  return __builtin_amdgcn_mfma_f32_16x16x32_bf16(a, b, c, 0, 0, 0);
}
__device__ __forceinline__ f32x4 mfma16(short4v a, short4v b, f32x4 c) {
  return __builtin_amdgcn_mfma_f32_16x16x16bf16_1k(a, b, c, 0, 0, 0);
}

// Layouts (bf16 element offsets):
// Q  B-frag(K=32), pre-scaled by C2_: ((b*256+tg)*2+ks)*512 + lane*8 + jj
// K  A-frag(K=32): ((b*64+kt)*8+jb*2+ks)*512 + lane*8+jj
// V^T A-frag(K=16) jb-paired: ((b*64+kt)*8 + cb*2+jp)*512 + lane*8 + (jb&1)*4 + r

// ---------------- Kernel 1: stats + integrated dtype probe ------------------
template <bool F32>
__device__ __forceinline__ void stats_sum(const void* x, int bc, int t,
                                          float& s, float& s2) {
  if (F32) {
    const float4* xp = (const float4*)((const float*)x + (size_t)bc * N_);
#pragma unroll
    for (int r = 0; r < 4; ++r) {
      const float4 v = xp[r * 256 + t];
      s += (v.x + v.y) + (v.z + v.w);
      s2 += (v.x * v.x + v.y * v.y) + (v.z * v.z + v.w * v.w);
    }
  } else {
    const bf16* xp = (const bf16*)x + (size_t)bc * N_;
#pragma unroll
    for (int r = 0; r < 2; ++r) {
      float f[8];
      up8(*(const short8*)(xp + (r * 256 + t) * 8), f);
#pragma unroll
      for (int i = 0; i < 8; ++i) { s += f[i]; s2 += f[i] * f[i]; }
    }
  }
}

__global__ __launch_bounds__(256) void k_stats(const void* __restrict__ x,
                                               float* __restrict__ meanArr,
                                               float* __restrict__ rstdArr,
                                               int* __restrict__ flag) {
  const int bc = blockIdx.x, t = threadIdx.x;
  __shared__ float ps[4], ps2[4];
  __shared__ int pflag;
  {
    const ushort* xw = (const ushort*)x + (size_t)bc * 4096;
    int cnt = 0;
#pragma unroll
    for (int j = 0; j < 4; ++j) {
      const ushort4 u = *(const ushort4*)(xw + t * 16 + j * 4);
      cnt += ((u.x >> 7) & 0xFF) >= 143;
      cnt += ((u.y >> 7) & 0xFF) >= 143;
      cnt += ((u.z >> 7) & 0xFF) >= 143;
      cnt += ((u.w >> 7) & 0xFF) >= 143;
    }
#pragma unroll
    for (int off = 32; off > 0; off >>= 1) cnt += __shfl_down(cnt, off, 64);
    if (t == 0) pflag = 0;
    __syncthreads();
    if ((t & 63) == 0 && cnt > 16) atomicAdd(&pflag, cnt);
    __syncthreads();
  }
  const bool f32 = pflag > 64;
  float s = 0.f, s2 = 0.f;
  if (f32) stats_sum<true>(x, bc, t, s, s2);
  else stats_sum<false>(x, bc, t, s, s2);
#pragma unroll
  for (int off = 32; off > 0; off >>= 1) {
    s += __shfl_down(s, off, 64);
    s2 += __shfl_down(s2, off, 64);
  }
  if ((t & 63) == 0) { ps[t >> 6] = s; ps2[t >> 6] = s2; }
  __syncthreads();
  if (t == 0) {
    const float S = (ps[0] + ps[1]) + (ps[2] + ps[3]);
    const float S2 = (ps2[0] + ps2[1]) + (ps2[2] + ps2[3]);
    const float mean = S * (1.0f / N_);
    const float var = S2 * (1.0f / N_) - mean * mean;
    meanArr[bc] = mean;
    rstdArr[bc] = rsqrtf(var + EPS_);
    flag[0] = f32 ? 1 : 0;
  }
}

// ---------------- Kernel 2: norm + qkv projection (MFMA) --------------------
template <bool F32>
__device__ __forceinline__ void qkv_body(const void* x, const void* wqkv,
                                         const void* bqkv, const float* meanArr,
                                         const float* rstdArr, bf16* q, bf16* k,
                                         bf16* v, short* HB) {
  const int t = threadIdx.x, tj = blockIdx.x, b = blockIdx.y;
  const int n0 = tj * 64;
  {
    const int li = t & 15, nbt = (t >> 4) & 3, cg = t >> 6;
    const int n = n0 + nbt * 16 + li;
    const float* mb_ = meanArr + b * 64;
    const float* rb_ = rstdArr + b * 64;
    float hv[16];
#pragma unroll
    for (int i = 0; i < 16; ++i) {
      const int c = cg * 16 + i;
      hv[i] = (ldx<F32>(x, ((size_t)(b * 64 + c)) * N_ + n) - mb_[c]) * rb_[c];
    }
#pragma unroll
    for (int c8 = 0; c8 < 2; ++c8) {
      const int ks = cg >> 1, qd = (cg & 1) * 2 + c8;
      *(short8*)&HB[((nbt * 2 + ks) * 64 + qd * 16 + li) * 8] = pk8(&hv[c8 * 8]);
    }
  }
  __syncthreads();
  const int l = t & 63, w = t >> 6, li = l & 15, quad = l >> 4;
  short8 Wf[3][2];
#pragma unroll
  for (int sec = 0; sec < 3; ++sec)
#pragma unroll
    for (int ks = 0; ks < 2; ++ks)
      Wf[sec][ks] = ld8<F32>(wqkv, (sec * 64 + w * 16 + li) * 64 + ks * 32 + quad * 8);
  short8 Hf[4][2];
#pragma unroll
  for (int nb = 0; nb < 4; ++nb)
#pragma unroll
    for (int ks = 0; ks < 2; ++ks)
      Hf[nb][ks] = *(const short8*)&HB[((nb * 2 + ks) * 64 + l) * 8];
  float bq[4], bk[4];
#pragma unroll
  for (int r = 0; r < 4; ++r) {
    bq[r] = ldx<F32>(bqkv, w * 16 + quad * 4 + r);
    bk[r] = ldx<F32>(bqkv, 64 + w * 16 + quad * 4 + r);
  }
  const float bv = ldx<F32>(bqkv, 128 + w * 16 + li);
  const int lhi = ((w & 1) * 2 + (quad >> 1)) * 16 + li;
  const int jj0 = (quad & 1) * 4;
#pragma unroll
  for (int nb = 0; nb < 4; ++nb) {
    f32x4 dq = {0.f, 0.f, 0.f, 0.f}, dk = dq, dv = dq;
    dq = mfma32(Wf[0][0], Hf[nb][0], dq);
    dq = mfma32(Wf[0][1], Hf[nb][1], dq);
    dk = mfma32(Wf[1][0], Hf[nb][0], dk);
    dk = mfma32(Wf[1][1], Hf[nb][1], dk);
    dv = mfma32(Hf[nb][0], Wf[2][0], dv);
    dv = mfma32(Hf[nb][1], Wf[2][1], dv);
    union { ushort4 u; short s[4]; } pq, pk_, pv;
#pragma unroll
    for (int r = 0; r < 4; ++r) {
      pq.s[r] = f2bs((dq[r] + bq[r]) * C2_);  // scale folded into q
      pk_.s[r] = f2bs(dk[r] + bk[r]);
      pv.s[r] = f2bs(dv[r] + bv);
    }
    *(ushort4*)&q[(((size_t)(b * 256 + tj * 4 + nb)) * 2 + (w >> 1)) * 512 + lhi * 8 + jj0] = pq.u;
    *(ushort4*)&k[(((size_t)(b * 64 + tj)) * 8 + nb * 2 + (w >> 1)) * 512 + lhi * 8 + jj0] = pk_.u;
    // V^T packed: chunk cb*2+jp (cb=w, jp=nb>>1), lane l, half (nb&1)
    *(ushort4*)&v[(((size_t)(b * 64 + tj)) * 8 + w * 2 + (nb >> 1)) * 512 + l * 8 + (nb & 1) * 4] = pv.u;
  }
}
__global__ __launch_bounds__(256) void k_qkv(
    const void* __restrict__ x, const void* __restrict__ wqkv,
    const void* __restrict__ bqkv, const float* __restrict__ meanArr,
    const float* __restrict__ rstdArr, bf16* __restrict__ q,
    bf16* __restrict__ k, bf16* __restrict__ v, const int* __restrict__ flag) {
  __shared__ short HB[4096];
  if (*flag) qkv_body<true>(x, wqkv, bqkv, meanArr, rstdArr, q, k, v, HB);
  else qkv_body<false>(x, wqkv, bqkv, meanArr, rstdArr, q, k, v, HB);
}

// ---------------- Kernel 3: MFMA attention, 64 q/wave, LDS-staged K/V -------
// grid 512: kh = bid&7 (XCD-locked key eighth), s=bid>>3: b=s&3, qt=s>>2.
// Block = 256 queries (wave w owns frags mb = w*4+q), 8 key tiles, dbuf LDS.
__device__ __forceinline__ void stage(short* dst, const bf16* ks_,
                                      const bf16* vs_, int w, int ln) {
#pragma unroll
  for (int i = 0; i < 2; ++i) {
    const int off = w * 1024 + i * 512;
    __builtin_amdgcn_global_load_lds(
        (const __attribute__((address_space(1))) unsigned int*)(ks_ + off + ln * 8),
        (__attribute__((address_space(3))) unsigned int*)(dst + off), 16, 0, 0);
    __builtin_amdgcn_global_load_lds(
        (const __attribute__((address_space(1))) unsigned int*)(vs_ + off + ln * 8),
        (__attribute__((address_space(3))) unsigned int*)(dst + 4096 + off), 16, 0, 0);
  }
}

__global__ __launch_bounds__(256, 2) void k_attn(
    const bf16* __restrict__ qg, const bf16* __restrict__ kg,
    const bf16* __restrict__ vg, bf16* __restrict__ opart,
    float* __restrict__ lpart) {
  __shared__ __align__(16) short KV[2][8192];
  const int bid = blockIdx.x;
  const int kh = bid & 7, s = bid >> 3;
  const int b = s & 3, qt = s >> 2;
  const int t = threadIdx.x, l = t & 63, w = t >> 6, li = l & 15, quad = l >> 4;

  short8 Qf[4][2];
#pragma unroll
  for (int q = 0; q < 4; ++q)
#pragma unroll
    for (int ks = 0; ks < 2; ++ks)
      Qf[q][ks] = *(const short8*)(qg +
          (((size_t)(b * 256 + qt * 16 + w * 4 + q)) * 2 + ks) * 512 + l * 8);

  f32x4 O[4][4];  // [cb][q]; C-layout row=c-within-16, col=token
#pragma unroll
  for (int cb = 0; cb < 4; ++cb)
#pragma unroll
    for (int q = 0; q < 4; ++q) O[cb][q] = {0.f, 0.f, 0.f, 0.f};
  float ls[4] = {0.f, 0.f, 0.f, 0.f};

  const bf16* kbase = kg + ((size_t)(b * 64 + kh * 8)) * 4096;
  const bf16* vbase = vg + ((size_t)(b * 64 + kh * 8)) * 4096;

  stage(&KV[0][0], kbase, vbase, w, l);
  __syncthreads();
  for (int it = 0; it < 8; ++it) {
    const short* buf = &KV[it & 1][0];
    if (it + 1 < 8)
      stage(&KV[(it + 1) & 1][0], kbase + (size_t)(it + 1) * 4096,
            vbase + (size_t)(it + 1) * 4096, w, l);
    short8 Kf[4][2];
#pragma unroll
    for (int jb = 0; jb < 4; ++jb)
#pragma unroll
      for (int ks = 0; ks < 2; ++ks)
        Kf[jb][ks] = *(const short8*)&buf[(jb * 2 + ks) * 512 + l * 8];
    short8 Vp[4][2];  // [cb][jp]; lo half = jb even, hi half = jb odd
#pragma unroll
    for (int cb = 0; cb < 4; ++cb)
#pragma unroll
      for (int jp = 0; jp < 2; ++jp)
        Vp[cb][jp] = *(const short8*)&buf[4096 + (cb * 2 + jp) * 512 + l * 8];
#pragma unroll
    for (int jb = 0; jb < 4; ++jb) {
      short4v Pf[4];
#pragma unroll
      for (int q = 0; q < 4; ++q) {
        f32x4 sv = {0.f, 0.f, 0.f, 0.f};
        sv = mfma32(Kf[jb][0], Qf[q][0], sv);
        sv = mfma32(Kf[jb][1], Qf[q][1], sv);
        const float p0 = exp2f(sv[0]), p1 = exp2f(sv[1]);
        const float p2 = exp2f(sv[2]), p3 = exp2f(sv[3]);
        ls[q] += (p0 + p1) + (p2 + p3);
        union { short4v v; __hip_bfloat162 h[2]; } pu;
        pu.h[0] = __float22bfloat162_rn(make_float2(p0, p1));
        pu.h[1] = __float22bfloat162_rn(make_float2(p2, p3));
        Pf[q] = pu.v;
      }
#pragma unroll
      for (int cb = 0; cb < 4; ++cb) {
        const short8 vp = Vp[cb][jb >> 1];
        const short4v vh = (jb & 1)
            ? __builtin_shufflevector(vp, vp, 4, 5, 6, 7)
            : __builtin_shufflevector(vp, vp, 0, 1, 2, 3);
#pragma unroll
        for (int q = 0; q < 4; ++q) O[cb][q] = mfma16(vh, Pf[q], O[cb][q]);
      }
    }
    __syncthreads();
  }
#pragma unroll
  for (int q = 0; q < 4; ++q) {
    ls[q] += __shfl_xor(ls[q], 16, 64);
    ls[q] += __shfl_xor(ls[q], 32, 64);
  }
  const size_t pb = ((size_t)(kh * 4 + b)) * 16 + qt;
  if (l < 16) {
#pragma unroll
    for (int q = 0; q < 4; ++q)
      lpart[(pb * 16 + w * 4 + q) * 16 + l] = ls[q];
  }
#pragma unroll
  for (int q = 0; q < 4; ++q)
#pragma unroll
    for (int cb = 0; cb < 4; ++cb) {
      union { ushort4 u; short s[4]; } pk_;
#pragma unroll
      for (int r = 0; r < 4; ++r) pk_.s[r] = f2bs(O[cb][q][r]);
      *(ushort4*)&opart[((pb * 16 + w * 4 + q) * 4 + cb) * 256 + l * 4] = pk_.u;
    }
}

// ---------------- Kernel 4: merge 8 key-parts + proj + residual -------------
template <bool F32>
__device__ __forceinline__ void proj_body(const bf16* opart, const float* lpart,
                                          const void* xg, const void* wp,
                                          const void* bp, void* outv) {
  const int qt64 = blockIdx.x, bb = blockIdx.y;
  const int qt = qt64 >> 2;
  const int t = threadIdx.x, l = t & 63, w = t >> 6, li = l & 15, quad = l >> 4;
  short8 Wa[2];
#pragma unroll
  for (int ks = 0; ks < 2; ++ks)
    Wa[ks] = ld8<F32>(wp, (w * 16 + li) * 64 + ks * 32 + quad * 8);
  float bpv[4];
#pragma unroll
  for (int r = 0; r < 4; ++r) bpv[r] = ldx<F32>(bp, w * 16 + quad * 4 + r);
  f32x4 D[4];
#pragma unroll
  for (int mb = 0; mb < 4; ++mb) {
    const int mbg = (qt64 & 3) * 4 + mb;
    float lv = 0.f;
#pragma unroll
    for (int p = 0; p < 8; ++p)
      lv += lpart[((((size_t)(p * 4 + bb)) * 16 + qt) * 16 + mbg) * 16 + li];
    lv = 1.0f / lv;
    f32x4 acc = {0.f, 0.f, 0.f, 0.f};
#pragma unroll
    for (int ks = 0; ks < 2; ++ks) {
      const int cb = ks * 2 + (quad >> 1);
      const int qs0 = (quad & 1) * 2;
      float s8[8] = {};
#pragma unroll
      for (int p = 0; p < 8; ++p) {
        const size_t base =
            (((((size_t)(p * 4 + bb)) * 16 + qt) * 16 + mbg) * 4 + cb) * 256;
        float f0[4], f1[4];
        up4(*(const ushort4*)&opart[base + (qs0 * 16 + li) * 4], f0);
        up4(*(const ushort4*)&opart[base + ((qs0 + 1) * 16 + li) * 4], f1);
#pragma unroll
        for (int i = 0; i < 4; ++i) { s8[i] += f0[i]; s8[4 + i] += f1[i]; }
      }
#pragma unroll
      for (int i = 0; i < 8; ++i) s8[i] *= lv;
      acc = mfma32(Wa[ks], pk8(s8), acc);
    }
    D[mb] = acc;
  }
#pragma unroll
  for (int mb = 0; mb < 4; ++mb)
#pragma unroll
    for (int r = 0; r < 4; ++r) {
      const int o = w * 16 + quad * 4 + r;
      const int n = qt64 * 64 + mb * 16 + li;
      const size_t idx = ((size_t)(bb * 64 + o)) * N_ + n;
      const float res = ldx<F32>(xg, idx) + D[mb][r] + bpv[r];
      if (F32) ((float*)outv)[idx] = res;
      else ((bf16*)outv)[idx] = __float2bfloat16(res);
    }
}
__global__ __launch_bounds__(256) void k_proj(
    const bf16* __restrict__ opart, const float* __restrict__ lpart,
    const void* __restrict__ xg, const void* __restrict__ wp,
    const void* __restrict__ bp, void* __restrict__ outv,
    const int* __restrict__ flag) {
  if (*flag) proj_body<true>(opart, lpart, xg, wp, bp, outv);
  else proj_body<false>(opart, lpart, xg, wp, bp, outv);
}

// ---------------- launcher --------------------------------------------------
extern "C" void kernel_launch(void* const* d_in, const int* in_sizes, int n_in,
                              void* d_out, int out_size, void* d_ws,
                              size_t ws_size, hipStream_t stream) {
  const void* x = d_in[0];
  const void* wqkv = d_in[1];
  const void* bqkv = d_in[2];
  const void* wproj = d_in[3];
  const void* bproj = d_in[4];

  char* ws = (char*)d_ws;
  float* meanArr = (float*)ws;                        // 1 KB
  float* rstdArr = (float*)(ws + 1024);               // 1 KB
  int* flag = (int*)(ws + 2048);
  bf16* q = (bf16*)(ws + 4096);                       // 2 MB
  bf16* k = (bf16*)(ws + 4096 + (2u << 20));          // 2 MB
  bf16* v = (bf16*)(ws + 4096 + (4u << 20));          // 2 MB
  bf16* opart = (bf16*)(ws + 4096 + (6u << 20));      // 8 parts: 16.8 MB
  float* lpart = (float*)(ws + 4096 + (23u << 20));   // 2 MB

  k_stats<<<256, 256, 0, stream>>>(x, meanArr, rstdArr, flag);
  k_qkv<<<dim3(64, 4), 256, 0, stream>>>(x, wqkv, bqkv, meanArr, rstdArr, q, k,
                                         v, flag);
  k_attn<<<512, 256, 0, stream>>>(q, k, v, opart, lpart);
  k_proj<<<dim3(64, 4), 256, 0, stream>>>(opart, lpart, x, wproj, bproj, d_out,
                                          flag);
}

// Round 8
// 113.518 us; speedup vs baseline: 1.0527x; 1.0527x over previous
//
#include <hip/hip_runtime.h>
#include <hip/hip_bf16.h>

#define B_ 4
#define C_ 64
#define N_ 4096
#define EPS_ 1e-5f
// p = exp(s*0.125) = exp2(s * 0.125*log2e); scale folded into stored q
#define C2_ 0.18033688011112042f

typedef __hip_bfloat16 bf16;
typedef __attribute__((ext_vector_type(8))) short short8;
typedef __attribute__((ext_vector_type(4))) short short4v;
typedef __attribute__((ext_vector_type(4))) float f32x4;

__device__ __forceinline__ float b2f(bf16 v) { return __bfloat162float(v); }

__device__ __forceinline__ short f2bs(float f) {
  union { bf16 h; short s; } u;
  u.h = __float2bfloat16(f);
  return u.s;
}

__device__ __forceinline__ short8 pk8(const float* f) {
  union { short8 v; short s[8]; } u;
#pragma unroll
  for (int i = 0; i < 8; ++i) u.s[i] = f2bs(f[i]);
  return u.v;
}

__device__ __forceinline__ void up8(short8 v, float* d) {
  union { short8 v; unsigned u[4]; } x;
  x.v = v;
  d[0] = __uint_as_float(x.u[0] << 16);
  d[1] = __uint_as_float(x.u[0] & 0xffff0000u);
  d[2] = __uint_as_float(x.u[1] << 16);
  d[3] = __uint_as_float(x.u[1] & 0xffff0000u);
  d[4] = __uint_as_float(x.u[2] << 16);
  d[5] = __uint_as_float(x.u[2] & 0xffff0000u);
  d[6] = __uint_as_float(x.u[3] << 16);
  d[7] = __uint_as_float(x.u[3] & 0xffff0000u);
}

__device__ __forceinline__ void up4(ushort4 u, float* d) {
  d[0] = __uint_as_float(((unsigned)u.x) << 16);
  d[1] = __uint_as_float(((unsigned)u.y) << 16);
  d[2] = __uint_as_float(((unsigned)u.z) << 16);
  d[3] = __uint_as_float(((unsigned)u.w) << 16);
}

template <bool F32>
__device__ __forceinline__ float ldx(const void* p, size_t idx) {
  if (F32) return ((const float*)p)[idx];
  return b2f(((const bf16*)p)[idx]);
}

template <bool F32>
__device__ __forceinline__ short8 ld8(const void* p, int idx) {
  if (F32) {
    const float* fp = (const float*)p + idx;
    float tmp[8];
    *(float4*)&tmp[0] = *(const float4*)fp;
    *(float4*)&tmp[4] = *(const float4*)(fp + 4);
    return pk8(tmp);
  }
  return *(const short8*)((const bf16*)p + idx);
}

__device__ __forceinline__ f32x4 mfma32(short8 a, short8 b, f32x4 c) {
  return __builtin_amdgcn_mfma_f32_16x16x32_bf16(a, b, c, 0, 0, 0);
}
__device__ __forceinline__ f32x4 mfma16(short4v a, short4v b, f32x4 c) {
  return __builtin_amdgcn_mfma_f32_16x16x16bf16_1k(a, b, c, 0, 0, 0);
}

// Layouts (bf16 element offsets):
// Q  B-frag(K=32), pre-scaled by C2_: ((b*256+tg)*2+ks)*512 + lane*8 + jj
// K  A-frag(K=32): ((b*64+kt)*8+jb*2+ks)*512 + lane*8+jj
// V^T A-frag(K=16) jb-paired: ((b*64+kt)*8 + cb*2+jp)*512 + lane*8 + (jb&1)*4 + r

// ---------------- Kernel 1: stats + integrated dtype probe ------------------
template <bool F32>
__device__ __forceinline__ void stats_sum(const void* x, int bc, int t,
                                          float& s, float& s2) {
  if (F32) {
    const float4* xp = (const float4*)((const float*)x + (size_t)bc * N_);
#pragma unroll
    for (int r = 0; r < 4; ++r) {
      const float4 v = xp[r * 256 + t];
      s += (v.x + v.y) + (v.z + v.w);
      s2 += (v.x * v.x + v.y * v.y) + (v.z * v.z + v.w * v.w);
    }
  } else {
    const bf16* xp = (const bf16*)x + (size_t)bc * N_;
#pragma unroll
    for (int r = 0; r < 2; ++r) {
      float f[8];
      up8(*(const short8*)(xp + (r * 256 + t) * 8), f);
#pragma unroll
      for (int i = 0; i < 8; ++i) { s += f[i]; s2 += f[i] * f[i]; }
    }
  }
}

__global__ __launch_bounds__(256) void k_stats(const void* __restrict__ x,
                                               float* __restrict__ meanArr,
                                               float* __restrict__ rstdArr,
                                               int* __restrict__ flag) {
  const int bc = blockIdx.x, t = threadIdx.x;
  __shared__ float ps[4], ps2[4];
  __shared__ int pflag;
  {
    const ushort* xw = (const ushort*)x + (size_t)bc * 4096;
    int cnt = 0;
#pragma unroll
    for (int j = 0; j < 4; ++j) {
      const ushort4 u = *(const ushort4*)(xw + t * 16 + j * 4);
      cnt += ((u.x >> 7) & 0xFF) >= 143;
      cnt += ((u.y >> 7) & 0xFF) >= 143;
      cnt += ((u.z >> 7) & 0xFF) >= 143;
      cnt += ((u.w >> 7) & 0xFF) >= 143;
    }
#pragma unroll
    for (int off = 32; off > 0; off >>= 1) cnt += __shfl_down(cnt, off, 64);
    if (t == 0) pflag = 0;
    __syncthreads();
    if ((t & 63) == 0 && cnt > 16) atomicAdd(&pflag, cnt);
    __syncthreads();
  }
  const bool f32 = pflag > 64;
  float s = 0.f, s2 = 0.f;
  if (f32) stats_sum<true>(x, bc, t, s, s2);
  else stats_sum<false>(x, bc, t, s, s2);
#pragma unroll
  for (int off = 32; off > 0; off >>= 1) {
    s += __shfl_down(s, off, 64);
    s2 += __shfl_down(s2, off, 64);
  }
  if ((t & 63) == 0) { ps[t >> 6] = s; ps2[t >> 6] = s2; }
  __syncthreads();
  if (t == 0) {
    const float S = (ps[0] + ps[1]) + (ps[2] + ps[3]);
    const float S2 = (ps2[0] + ps2[1]) + (ps2[2] + ps2[3]);
    const float mean = S * (1.0f / N_);
    const float var = S2 * (1.0f / N_) - mean * mean;
    meanArr[bc] = mean;
    rstdArr[bc] = rsqrtf(var + EPS_);
    flag[0] = f32 ? 1 : 0;
  }
}

// ---------------- Kernel 2: norm + qkv projection (MFMA) --------------------
template <bool F32>
__device__ __forceinline__ void qkv_body(const void* x, const void* wqkv,
                                         const void* bqkv, const float* meanArr,
                                         const float* rstdArr, bf16* q, bf16* k,
                                         bf16* v, short* HB) {
  const int t = threadIdx.x, tj = blockIdx.x, b = blockIdx.y;
  const int n0 = tj * 64;
  {
    const int li = t & 15, nbt = (t >> 4) & 3, cg = t >> 6;
    const int n = n0 + nbt * 16 + li;
    const float* mb_ = meanArr + b * 64;
    const float* rb_ = rstdArr + b * 64;
    float hv[16];
#pragma unroll
    for (int i = 0; i < 16; ++i) {
      const int c = cg * 16 + i;
      hv[i] = (ldx<F32>(x, ((size_t)(b * 64 + c)) * N_ + n) - mb_[c]) * rb_[c];
    }
#pragma unroll
    for (int c8 = 0; c8 < 2; ++c8) {
      const int ks = cg >> 1, qd = (cg & 1) * 2 + c8;
      *(short8*)&HB[((nbt * 2 + ks) * 64 + qd * 16 + li) * 8] = pk8(&hv[c8 * 8]);
    }
  }
  __syncthreads();
  const int l = t & 63, w = t >> 6, li = l & 15, quad = l >> 4;
  short8 Wf[3][2];
#pragma unroll
  for (int sec = 0; sec < 3; ++sec)
#pragma unroll
    for (int ks = 0; ks < 2; ++ks)
      Wf[sec][ks] = ld8<F32>(wqkv, (sec * 64 + w * 16 + li) * 64 + ks * 32 + quad * 8);
  short8 Hf[4][2];
#pragma unroll
  for (int nb = 0; nb < 4; ++nb)
#pragma unroll
    for (int ks = 0; ks < 2; ++ks)
      Hf[nb][ks] = *(const short8*)&HB[((nb * 2 + ks) * 64 + l) * 8];
  float bq[4], bk[4];
#pragma unroll
  for (int r = 0; r < 4; ++r) {
    bq[r] = ldx<F32>(bqkv, w * 16 + quad * 4 + r);
    bk[r] = ldx<F32>(bqkv, 64 + w * 16 + quad * 4 + r);
  }
  const float bv = ldx<F32>(bqkv, 128 + w * 16 + li);
  const int lhi = ((w & 1) * 2 + (quad >> 1)) * 16 + li;
  const int jj0 = (quad & 1) * 4;
#pragma unroll
  for (int nb = 0; nb < 4; ++nb) {
    f32x4 dq = {0.f, 0.f, 0.f, 0.f}, dk = dq, dv = dq;
    dq = mfma32(Wf[0][0], Hf[nb][0], dq);
    dq = mfma32(Wf[0][1], Hf[nb][1], dq);
    dk = mfma32(Wf[1][0], Hf[nb][0], dk);
    dk = mfma32(Wf[1][1], Hf[nb][1], dk);
    dv = mfma32(Hf[nb][0], Wf[2][0], dv);
    dv = mfma32(Hf[nb][1], Wf[2][1], dv);
    union { ushort4 u; short s[4]; } pq, pk_, pv;
#pragma unroll
    for (int r = 0; r < 4; ++r) {
      pq.s[r] = f2bs((dq[r] + bq[r]) * C2_);  // scale folded into q
      pk_.s[r] = f2bs(dk[r] + bk[r]);
      pv.s[r] = f2bs(dv[r] + bv);
    }
    *(ushort4*)&q[(((size_t)(b * 256 + tj * 4 + nb)) * 2 + (w >> 1)) * 512 + lhi * 8 + jj0] = pq.u;
    *(ushort4*)&k[(((size_t)(b * 64 + tj)) * 8 + nb * 2 + (w >> 1)) * 512 + lhi * 8 + jj0] = pk_.u;
    *(ushort4*)&v[(((size_t)(b * 64 + tj)) * 8 + w * 2 + (nb >> 1)) * 512 + l * 8 + (nb & 1) * 4] = pv.u;
  }
}
__global__ __launch_bounds__(256) void k_qkv(
    const void* __restrict__ x, const void* __restrict__ wqkv,
    const void* __restrict__ bqkv, const float* __restrict__ meanArr,
    const float* __restrict__ rstdArr, bf16* __restrict__ q,
    bf16* __restrict__ k, bf16* __restrict__ v, const int* __restrict__ flag) {
  __shared__ short HB[4096];
  if (*flag) qkv_body<true>(x, wqkv, bqkv, meanArr, rstdArr, q, k, v, HB);
  else qkv_body<false>(x, wqkv, bqkv, meanArr, rstdArr, q, k, v, HB);
}

// ---------------- Kernel 3: MFMA attention, 32 q/wave, 4 blocks/CU ----------
// grid 1024: kh = bid&7 (XCD-locked key eighth), b = (bid>>3)&3, qt = bid>>5.
// Block = 128 queries (wave w owns 16-token frags w*2+q), 8 key tiles, dbuf.
__device__ __forceinline__ void stage(short* dst, const bf16* ks_,
                                      const bf16* vs_, int w, int ln) {
#pragma unroll
  for (int i = 0; i < 2; ++i) {
    const int off = w * 1024 + i * 512;
    __builtin_amdgcn_global_load_lds(
        (const __attribute__((address_space(1))) unsigned int*)(ks_ + off + ln * 8),
        (__attribute__((address_space(3))) unsigned int*)(dst + off), 16, 0, 0);
    __builtin_amdgcn_global_load_lds(
        (const __attribute__((address_space(1))) unsigned int*)(vs_ + off + ln * 8),
        (__attribute__((address_space(3))) unsigned int*)(dst + 4096 + off), 16, 0, 0);
  }
}

__global__ __launch_bounds__(256, 4) void k_attn(
    const bf16* __restrict__ qg, const bf16* __restrict__ kg,
    const bf16* __restrict__ vg, bf16* __restrict__ opart,
    float* __restrict__ lpart) {
  __shared__ __align__(16) short KV[2][8192];
  const int bid = blockIdx.x;
  const int kh = bid & 7, b = (bid >> 3) & 3, qt = bid >> 5;
  const int t = threadIdx.x, l = t & 63, w = t >> 6, li = l & 15;

  short8 Qf[2][2];
#pragma unroll
  for (int q = 0; q < 2; ++q)
#pragma unroll
    for (int ks = 0; ks < 2; ++ks)
      Qf[q][ks] = *(const short8*)(qg +
          (((size_t)(b * 256 + qt * 8 + w * 2 + q)) * 2 + ks) * 512 + l * 8);

  f32x4 O[4][2];  // [cb][q]; C-layout row=c-within-16, col=token
#pragma unroll
  for (int cb = 0; cb < 4; ++cb)
#pragma unroll
    for (int q = 0; q < 2; ++q) O[cb][q] = {0.f, 0.f, 0.f, 0.f};
  float ls[2] = {0.f, 0.f};

  const bf16* kbase = kg + ((size_t)(b * 64 + kh * 8)) * 4096;
  const bf16* vbase = vg + ((size_t)(b * 64 + kh * 8)) * 4096;

  stage(&KV[0][0], kbase, vbase, w, l);
  __syncthreads();
  for (int it = 0; it < 8; ++it) {
    const short* buf = &KV[it & 1][0];
    if (it + 1 < 8)
      stage(&KV[(it + 1) & 1][0], kbase + (size_t)(it + 1) * 4096,
            vbase + (size_t)(it + 1) * 4096, w, l);
#pragma unroll
    for (int jp = 0; jp < 2; ++jp) {
      short8 Vp[4];
#pragma unroll
      for (int cb = 0; cb < 4; ++cb)
        Vp[cb] = *(const short8*)&buf[4096 + (cb * 2 + jp) * 512 + l * 8];
#pragma unroll
      for (int jh = 0; jh < 2; ++jh) {
        const int jb = jp * 2 + jh;
        const short8 Kf0 = *(const short8*)&buf[(jb * 2 + 0) * 512 + l * 8];
        const short8 Kf1 = *(const short8*)&buf[(jb * 2 + 1) * 512 + l * 8];
        short4v Pf[2];
#pragma unroll
        for (int q = 0; q < 2; ++q) {
          f32x4 sv = {0.f, 0.f, 0.f, 0.f};
          sv = mfma32(Kf0, Qf[q][0], sv);
          sv = mfma32(Kf1, Qf[q][1], sv);
          const float p0 = exp2f(sv[0]), p1 = exp2f(sv[1]);
          const float p2 = exp2f(sv[2]), p3 = exp2f(sv[3]);
          ls[q] += (p0 + p1) + (p2 + p3);
          union { short4v v; __hip_bfloat162 h[2]; } pu;
          pu.h[0] = __float22bfloat162_rn(make_float2(p0, p1));
          pu.h[1] = __float22bfloat162_rn(make_float2(p2, p3));
          Pf[q] = pu.v;
        }
#pragma unroll
        for (int cb = 0; cb < 4; ++cb) {
          const short4v vh = jh
              ? __builtin_shufflevector(Vp[cb], Vp[cb], 4, 5, 6, 7)
              : __builtin_shufflevector(Vp[cb], Vp[cb], 0, 1, 2, 3);
          O[cb][0] = mfma16(vh, Pf[0], O[cb][0]);
          O[cb][1] = mfma16(vh, Pf[1], O[cb][1]);
        }
      }
    }
    __syncthreads();
  }
#pragma unroll
  for (int q = 0; q < 2; ++q) {
    ls[q] += __shfl_xor(ls[q], 16, 64);
    ls[q] += __shfl_xor(ls[q], 32, 64);
  }
  const size_t pb = ((size_t)(kh * 4 + b)) * 32 + qt;
  if (l < 16) {
#pragma unroll
    for (int q = 0; q < 2; ++q)
      lpart[(pb * 8 + w * 2 + q) * 16 + l] = ls[q];
  }
#pragma unroll
  for (int q = 0; q < 2; ++q)
#pragma unroll
    for (int cb = 0; cb < 4; ++cb) {
      union { ushort4 u; short s[4]; } pk_;
#pragma unroll
      for (int r = 0; r < 4; ++r) pk_.s[r] = f2bs(O[cb][q][r]);
      *(ushort4*)&opart[((pb * 8 + w * 2 + q) * 4 + cb) * 256 + l * 4] = pk_.u;
    }
}

// ---------------- Kernel 4: merge 8 key-parts + proj + residual -------------
template <bool F32>
__device__ __forceinline__ void proj_body(const bf16* opart, const float* lpart,
                                          const void* xg, const void* wp,
                                          const void* bp, void* outv) {
  const int qt64 = blockIdx.x, bb = blockIdx.y;
  const int qt = qt64 >> 1;
  const int t = threadIdx.x, l = t & 63, w = t >> 6, li = l & 15, quad = l >> 4;
  short8 Wa[2];
#pragma unroll
  for (int ks = 0; ks < 2; ++ks)
    Wa[ks] = ld8<F32>(wp, (w * 16 + li) * 64 + ks * 32 + quad * 8);
  float bpv[4];
#pragma unroll
  for (int r = 0; r < 4; ++r) bpv[r] = ldx<F32>(bp, w * 16 + quad * 4 + r);
  f32x4 D[4];
#pragma unroll
  for (int mb = 0; mb < 4; ++mb) {
    const int mbg = (qt64 & 1) * 4 + mb;
    float lv = 0.f;
#pragma unroll
    for (int p = 0; p < 8; ++p)
      lv += lpart[((((size_t)(p * 4 + bb)) * 32 + qt) * 8 + mbg) * 16 + li];
    lv = 1.0f / lv;
    f32x4 acc = {0.f, 0.f, 0.f, 0.f};
#pragma unroll
    for (int ks = 0; ks < 2; ++ks) {
      const int cb = ks * 2 + (quad >> 1);
      const int qs0 = (quad & 1) * 2;
      float s8[8] = {};
#pragma unroll
      for (int p = 0; p < 8; ++p) {
        const size_t base =
            (((((size_t)(p * 4 + bb)) * 32 + qt) * 8 + mbg) * 4 + cb) * 256;
        float f0[4], f1[4];
        up4(*(const ushort4*)&opart[base + (qs0 * 16 + li) * 4], f0);
        up4(*(const ushort4*)&opart[base + ((qs0 + 1) * 16 + li) * 4], f1);
#pragma unroll
        for (int i = 0; i < 4; ++i) { s8[i] += f0[i]; s8[4 + i] += f1[i]; }
      }
#pragma unroll
      for (int i = 0; i < 8; ++i) s8[i] *= lv;
      acc = mfma32(Wa[ks], pk8(s8), acc);
    }
    D[mb] = acc;
  }
#pragma unroll
  for (int mb = 0; mb < 4; ++mb)
#pragma unroll
    for (int r = 0; r < 4; ++r) {
      const int o = w * 16 + quad * 4 + r;
      const int n = qt64 * 64 + mb * 16 + li;
      const size_t idx = ((size_t)(bb * 64 + o)) * N_ + n;
      const float res = ldx<F32>(xg, idx) + D[mb][r] + bpv[r];
      if (F32) ((float*)outv)[idx] = res;
      else ((bf16*)outv)[idx] = __float2bfloat16(res);
    }
}
__global__ __launch_bounds__(256) void k_proj(
    const bf16* __restrict__ opart, const float* __restrict__ lpart,
    const void* __restrict__ xg, const void* __restrict__ wp,
    const void* __restrict__ bp, void* __restrict__ outv,
    const int* __restrict__ flag) {
  if (*flag) proj_body<true>(opart, lpart, xg, wp, bp, outv);
  else proj_body<false>(opart, lpart, xg, wp, bp, outv);
}

// ---------------- launcher --------------------------------------------------
extern "C" void kernel_launch(void* const* d_in, const int* in_sizes, int n_in,
                              void* d_out, int out_size, void* d_ws,
                              size_t ws_size, hipStream_t stream) {
  const void* x = d_in[0];
  const void* wqkv = d_in[1];
  const void* bqkv = d_in[2];
  const void* wproj = d_in[3];
  const void* bproj = d_in[4];

  char* ws = (char*)d_ws;
  float* meanArr = (float*)ws;                        // 1 KB
  float* rstdArr = (float*)(ws + 1024);               // 1 KB
  int* flag = (int*)(ws + 2048);
  bf16* q = (bf16*)(ws + 4096);                       // 2 MB
  bf16* k = (bf16*)(ws + 4096 + (2u << 20));          // 2 MB
  bf16* v = (bf16*)(ws + 4096 + (4u << 20));          // 2 MB
  bf16* opart = (bf16*)(ws + 4096 + (6u << 20));      // 16 MB (8 parts)
  float* lpart = (float*)(ws + 4096 + (22u << 20));   // 512 KB

  k_stats<<<256, 256, 0, stream>>>(x, meanArr, rstdArr, flag);
  k_qkv<<<dim3(64, 4), 256, 0, stream>>>(x, wqkv, bqkv, meanArr, rstdArr, q, k,
                                         v, flag);
  k_attn<<<1024, 256, 0, stream>>>(q, k, v, opart, lpart);
  k_proj<<<dim3(64, 4), 256, 0, stream>>>(opart, lpart, x, wproj, bproj, d_out,
                                          flag);
}